// Round 4
// baseline (472.590 us; speedup 1.0000x reference)
//
#include <hip/hip_runtime.h>
#include <hip/hip_bf16.h>

// Effi_MVS: B=1, V=5, C=32, D=48, H=128, W=160, RATIO=8. fp32 in, fp32 out.
// Round 4:
//  - k_transpose: features -> channel-last featT[v][pix][32] so warp gathers
//    become dwordx4 with immediate offsets (544 scalar loads -> 136 x4 loads).
//  - k_warpvar: block = 320 = 2 image rows; after the 27-tap channel
//    contraction, fold the 3 x-taps via LDS -> write only 9 planes U (17.7 MB
//    instead of 53 MB).
//  - k_conv: 9 coalesced bf16 loads/output (was 27).
//  - k_upsample: block=(y,dy), lanes along x => coalesced mask reads; row
//    staged in LDS => coalesced output writes.

#define NV 5
#define NC 32
#define ND 48
#define NH 128
#define NW 160
#define HW (NH * NW)
#define DHW (ND * HW)

typedef __attribute__((ext_vector_type(2))) float f32x2;
typedef __attribute__((ext_vector_type(4))) float f32x4;

// ws layout (bytes)
#define OFF_M      0          // float M[4][12]
#define OFF_WF     256        // float wf[32][28]
#define OFF_DEPTHF 4096       // float depthf[20480]          (ends 86016)
#define OFF_PRE    86016      // float pre[DHW]               (ends 4018176)
#define OFF_FEATT  4018176    // float featT[5][HW][32]       (ends 17125376)
#define OFF_U      17125376   // bf16 U[9][DHW]               (ends 34820096)
// total 34.8 MB (< 57.1 MB proven available)

// ---------------------------------------------------------------- K1: setup
__global__ void k_setup(const float* __restrict__ proj,
                        const float* __restrict__ wreg,
                        float* __restrict__ M, float* __restrict__ wf) {
  if (threadIdx.x != 0) return;
  double P[NV][2][4][4];
  for (int v = 0; v < NV; ++v)
    for (int m = 0; m < 2; ++m)
      for (int i = 0; i < 4; ++i)
        for (int j = 0; j < 4; ++j)
          P[v][m][i][j] = (double)proj[((v * 2 + m) * 4 + i) * 4 + j];
  double C[NV][4][4];
  for (int v = 0; v < NV; ++v) {
    for (int i = 0; i < 4; ++i)
      for (int j = 0; j < 4; ++j) C[v][i][j] = P[v][0][i][j];
    for (int i = 0; i < 3; ++i)
      for (int j = 0; j < 4; ++j) {
        double s = 0.0;
        for (int k = 0; k < 3; ++k) s += P[v][1][i][k] * P[v][0][k][j];
        C[v][i][j] = s;
      }
  }
  double a[4][8];
  for (int i = 0; i < 4; ++i)
    for (int j = 0; j < 4; ++j) { a[i][j] = C[0][i][j]; a[i][j + 4] = (i == j) ? 1.0 : 0.0; }
  for (int col = 0; col < 4; ++col) {
    int piv = col; double best = fabs(a[col][col]);
    for (int r = col + 1; r < 4; ++r) { double v = fabs(a[r][col]); if (v > best) { best = v; piv = r; } }
    if (piv != col)
      for (int j = 0; j < 8; ++j) { double t = a[col][j]; a[col][j] = a[piv][j]; a[piv][j] = t; }
    double pv = a[col][col];
    for (int j = 0; j < 8; ++j) a[col][j] /= pv;
    for (int r = 0; r < 4; ++r) if (r != col) {
      double f = a[r][col];
      for (int j = 0; j < 8; ++j) a[r][j] -= f * a[col][j];
    }
  }
  double inv[4][4];
  for (int i = 0; i < 4; ++i)
    for (int j = 0; j < 4; ++j) inv[i][j] = a[i][j + 4];
  for (int v = 1; v < NV; ++v) {
    float* m = M + (v - 1) * 12;
    for (int i = 0; i < 3; ++i) {
      double r[4] = {0, 0, 0, 0};
      for (int k = 0; k < 4; ++k) {
        double cv = C[v][i][k];
        for (int j = 0; j < 4; ++j) r[j] += cv * inv[k][j];
      }
      m[i * 3 + 0] = (float)r[0]; m[i * 3 + 1] = (float)r[1]; m[i * 3 + 2] = (float)r[2];
      m[9 + i] = (float)r[3];
    }
  }
  for (int c = 0; c < NC; ++c) {
    for (int t = 0; t < 27; ++t) wf[c * 28 + t] = wreg[c * 27 + t];
    wf[c * 28 + 27] = 0.f;
  }
}

// ---------------------------------------------- K1b: channel-last transpose
__global__ __launch_bounds__(256) void k_transpose(const float* __restrict__ feat,
                                                   float* __restrict__ featT) {
  int v = blockIdx.x / 80;
  int pix0 = (blockIdx.x % 80) * 256;
  int pix = pix0 + threadIdx.x;
  float r[NC];
#pragma unroll
  for (int c = 0; c < NC; ++c)
    r[c] = feat[((size_t)(v * NC + c)) * HW + pix];   // coalesced per c
  float* dst = featT + ((size_t)v * HW + pix) * NC;
#pragma unroll
  for (int g = 0; g < 8; ++g) {
    f32x4 val; val.x = r[4*g]; val.y = r[4*g+1]; val.z = r[4*g+2]; val.w = r[4*g+3];
    *(f32x4*)(dst + 4 * g) = val;
  }
}

// ---------------------- K2: warp + variance + contract + x-fold (block=320)
__global__ __launch_bounds__(320) void k_warpvar(
    const float* __restrict__ featT,   // [5][HW][32]
    const float* __restrict__ depthv,  // [48]
    const float* __restrict__ M,       // [4][12]
    const float* __restrict__ wf,      // [32][28]
    __hip_bfloat16* __restrict__ U)    // [9][DHW]
{
  __shared__ float lds[27 * 320];
  int tid = threadIdx.x;
  int d = blockIdx.x / 64;                       // 64 blocks per depth slice
  int rem = (blockIdx.x % 64) * 320 + tid;       // pixel index in [0, HW)
  int y = rem / NW;
  int x = rem % NW;
  int idx = d * HW + rem;
  float xf = (float)x, yf = (float)y;
  float df = depthv[d];

  const float* cp[16];
  float cw[16];
#pragma unroll
  for (int v = 0; v < 4; ++v) {
    const float* m = M + v * 12;
    float rx = m[0] * xf + m[1] * yf + m[2];
    float ry = m[3] * xf + m[4] * yf + m[5];
    float rz = m[6] * xf + m[7] * yf + m[8];
    float px = rx * df + m[9];
    float py = ry * df + m[10];
    float pz = rz * df + m[11];
    float gx = px / pz;
    float gy = py / pz;
    float x0 = floorf(gx), y0 = floorf(gy);
    float wx = gx - x0, wy = gy - y0;
    float cxs[2] = {x0, x0 + 1.f}, cys[2] = {y0, y0 + 1.f};
    float wxs[2] = {1.f - wx, wx}, wys[2] = {1.f - wy, wy};
#pragma unroll
    for (int cy = 0; cy < 2; ++cy)
#pragma unroll
      for (int cx = 0; cx < 2; ++cx) {
        float fx = cxs[cx], fy = cys[cy];
        bool valid = (fx >= 0.f) && (fx <= (float)(NW - 1)) &&
                     (fy >= 0.f) && (fy <= (float)(NH - 1));
        float fxc = fminf(fmaxf(fx, 0.f), (float)(NW - 1));
        float fyc = fminf(fmaxf(fy, 0.f), (float)(NH - 1));
        int xi = (int)fxc, yi = (int)fyc;
        cp[v * 4 + cy * 2 + cx] = featT + ((size_t)(v + 1) * HW + yi * NW + xi) * NC;
        cw[v * 4 + cy * 2 + cx] = wxs[cx] * wys[cy] * (valid ? 1.f : 0.f);
      }
  }
  const float* rp = featT + (size_t)rem * NC;   // view 0 (ref)

  f32x2 wv2[14];
#pragma unroll
  for (int u = 0; u < 14; ++u) wv2[u] = (f32x2){0.f, 0.f};

#pragma unroll
  for (int g = 0; g < 8; ++g) {                 // 4 channels per group
    f32x4 rv = *(const f32x4*)(rp + 4 * g);
    f32x4 vs = rv;
    f32x4 vq = rv * rv;
#pragma unroll
    for (int v = 0; v < 4; ++v) {
      f32x4 l0 = *(const f32x4*)(cp[4 * v + 0] + 4 * g);
      f32x4 l1 = *(const f32x4*)(cp[4 * v + 1] + 4 * g);
      f32x4 l2 = *(const f32x4*)(cp[4 * v + 2] + 4 * g);
      f32x4 l3 = *(const f32x4*)(cp[4 * v + 3] + 4 * g);
      f32x4 val = l0 * cw[4 * v + 0] + l1 * cw[4 * v + 1]
                + l2 * cw[4 * v + 2] + l3 * cw[4 * v + 3];
      vs += val;
      vq += val * val;
    }
    f32x4 vsn = vs * 0.2f;
    f32x4 var = vq * 0.2f - vsn * vsn;
#pragma unroll
    for (int cc = 0; cc < 4; ++cc) {
      const f32x2* wr = (const f32x2*)(wf + (4 * g + cc) * 28);
      float vv = var[cc];
      f32x2 vb; vb.x = vv; vb.y = vv;
#pragma unroll
      for (int u = 0; u < 14; ++u) wv2[u] += wr[u] * vb;
    }
  }

  // x-fold: U_{dd,i}(x) = sum_j valid(x+j-1) * WV_{dd,i,j}(x+j-1)
#pragma unroll
  for (int t = 0; t < 27; ++t)
    lds[t * 320 + tid] = (t & 1) ? wv2[t >> 1].y : wv2[t >> 1].x;
  __syncthreads();

  bool xm = (x > 0), xp = (x < NW - 1);
  int tl = xm ? tid - 1 : tid;
  int tr = xp ? tid + 1 : tid;
#pragma unroll
  for (int t9 = 0; t9 < 9; ++t9) {
    // tap j sampled at x+j-1: j=0 from left neighbor's WV_{t9,0}, etc.
    float s = lds[(t9 * 3 + 1) * 320 + tid];
    float sl = lds[(t9 * 3 + 0) * 320 + tl];
    float sr = lds[(t9 * 3 + 2) * 320 + tr];
    s += (xm ? sl : 0.f) + (xp ? sr : 0.f);
    U[(size_t)t9 * DHW + idx] = __float2bfloat16(s);
  }
}

// ------------------------------------------------- K3a: 9-tap gather (d,y)
__global__ __launch_bounds__(256) void k_conv(const __hip_bfloat16* __restrict__ U,
                                              float* __restrict__ pre) {
  int idx = blockIdx.x * 256 + threadIdx.x;
  int x = idx % NW;
  int t1 = idx / NW;
  int y = t1 % NH;
  int d = t1 / NH;
  float acc = 0.f;
#pragma unroll
  for (int dd = 0; dd < 3; ++dd) {
    int dp = d + dd - 1;
    bool dok = (dp >= 0) && (dp < ND);
    int dpc = min(max(dp, 0), ND - 1);
#pragma unroll
    for (int i = 0; i < 3; ++i) {
      int yp = y + i - 1;
      bool yok = (yp >= 0) && (yp < NH);
      int ypc = min(max(yp, 0), NH - 1);
      int t9 = dd * 3 + i;
      float v = __bfloat162float(U[(size_t)t9 * DHW + dpc * HW + ypc * NW + x]);
      acc += (dok && yok) ? v : 0.f;
    }
  }
  pre[idx] = acc;
}

// ---------------------------------------- K3b: softmax over D + depth + conf
__global__ __launch_bounds__(256) void k_softmax(const float* __restrict__ pre,
                                                 const float* __restrict__ depthv,
                                                 float* __restrict__ depthf,
                                                 float* __restrict__ out_depth,
                                                 float* __restrict__ out_conf) {
  int p = blockIdx.x * 256 + threadIdx.x;
  float pr[ND];
  float m = -1e30f;
#pragma unroll
  for (int d = 0; d < ND; ++d) { pr[d] = pre[d * HW + p]; m = fmaxf(m, pr[d]); }
  float s = 0.f;
#pragma unroll
  for (int d = 0; d < ND; ++d) { pr[d] = expf(pr[d] - m); s += pr[d]; }
  float inv = 1.f / s;
  float dep = 0.f, ti = 0.f;
#pragma unroll
  for (int d = 0; d < ND; ++d) {
    float prob = pr[d] * inv;
    pr[d] = prob;
    dep += prob * depthv[d];
    ti += prob * (float)d;
  }
  int di = (int)ti;
  di = di < 0 ? 0 : (di > ND - 1 ? ND - 1 : di);
  float conf = 0.f;
#pragma unroll
  for (int d = 0; d < ND; ++d)
    conf += (d >= di - 1 && d <= di + 2) ? pr[d] : 0.f;
  depthf[p] = dep;
  out_depth[p] = dep;
  out_conf[p] = conf;
}

// ------------------------------- K4: convex upsample, block=(y,dy), 640 thr
__global__ __launch_bounds__(640) void k_upsample(const float* __restrict__ mask,
                                                  const float* __restrict__ depthf,
                                                  float* __restrict__ out) {
  __shared__ float row[NW * 8];
  int y = blockIdx.x >> 3;
  int dy = blockIdx.x & 7;
#pragma unroll
  for (int rep = 0; rep < 2; ++rep) {
    int lin = rep * 640 + threadIdx.x;     // [0, 1280)
    int dx = lin / NW;
    int x = lin % NW;
    float mv[9];
    float mmax = -1e30f;
#pragma unroll
    for (int k = 0; k < 9; ++k) {
      mv[k] = mask[(size_t)(k * 64 + dy * 8 + dx) * HW + y * NW + x];  // coalesced in x
      mmax = fmaxf(mmax, mv[k]);
    }
    float s = 0.f;
#pragma unroll
    for (int k = 0; k < 9; ++k) { mv[k] = expf(mv[k] - mmax); s += mv[k]; }
    float acc = 0.f;
#pragma unroll
    for (int k = 0; k < 9; ++k) {
      int ky = y + k / 3 - 1;
      int kx = x + k % 3 - 1;
      bool ok = (ky >= 0) && (ky < NH) && (kx >= 0) && (kx < NW);
      int kyc = min(max(ky, 0), NH - 1);
      int kxc = min(max(kx, 0), NW - 1);
      float dv = depthf[kyc * NW + kxc];
      acc += mv[k] * (ok ? dv : 0.f);
    }
    row[x * 8 + dx] = acc / s;
  }
  __syncthreads();
  float* orow = out + (size_t)(y * 8 + dy) * (NW * 8);
#pragma unroll
  for (int rep = 0; rep < 2; ++rep) {
    int j = rep * 640 + threadIdx.x;
    orow[j] = row[j];                      // coalesced
  }
}

// ---------------------------------------------------------------- launcher
extern "C" void kernel_launch(void* const* d_in, const int* in_sizes, int n_in,
                              void* d_out, int out_size, void* d_ws, size_t ws_size,
                              hipStream_t stream) {
  const float* feat   = (const float*)d_in[0];
  const float* proj   = (const float*)d_in[1];
  const float* depthv = (const float*)d_in[2];
  const float* mask   = (const float*)d_in[3];
  const float* wreg   = (const float*)d_in[4];

  char* ws = (char*)d_ws;
  float* M       = (float*)(ws + OFF_M);
  float* wf      = (float*)(ws + OFF_WF);
  float* depthf  = (float*)(ws + OFF_DEPTHF);
  float* pre     = (float*)(ws + OFF_PRE);
  float* featT   = (float*)(ws + OFF_FEATT);
  __hip_bfloat16* U = (__hip_bfloat16*)(ws + OFF_U);

  float* out = (float*)d_out;
  float* out_depth = out + (NH * 8) * (NW * 8);
  float* out_conf  = out_depth + HW;

  k_setup<<<1, 64, 0, stream>>>(proj, wreg, M, wf);
  k_transpose<<<NV * 80, 256, 0, stream>>>(feat, featT);
  k_warpvar<<<DHW / 320, 320, 0, stream>>>(featT, depthv, M, wf, U);
  k_conv<<<DHW / 256, 256, 0, stream>>>(U, pre);
  k_softmax<<<HW / 256, 256, 0, stream>>>(pre, depthv, depthf, out_depth, out_conf);
  k_upsample<<<NH * 8, 640, 0, stream>>>(mask, depthf, out);
}

// Round 5
// 340.935 us; speedup vs baseline: 1.3862x; 1.3862x over previous
//
#include <hip/hip_runtime.h>
#include <hip/hip_bf16.h>

// Effi_MVS: B=1, V=5, C=32, D=48, H=128, W=160, RATIO=8. fp32 in, fp32 out.
// Round 5 (consolidation):
//  - k_warpvar: channel-FIRST gathers (r3 layout — r4's channel-last transpose
//    destroyed wave-level coalescing: VALUBusy 62->15%, 150->363 us; reverted)
//    + x-fold of the conv through bf16 LDS (r4 idea, kept): writes 9 planes
//    (17.7 MB) instead of 27 (53 MB). LDS 17.3 KB/block -> 8 blocks/CU.
//  - k_conv: 9 coalesced bf16 loads/output.
//  - k_upsample: block=(y,dy), lanes along x => coalesced mask reads (r4).

#define NV 5
#define NC 32
#define ND 48
#define NH 128
#define NW 160
#define HW (NH * NW)
#define DHW (ND * HW)

typedef __attribute__((ext_vector_type(2))) float f32x2;

// ws layout (bytes)
#define OFF_M      0          // float M[4][12]
#define OFF_WF     256        // float wf[32][28]
#define OFF_DEPTHF 4096       // float depthf[20480]          (ends 86016)
#define OFF_PRE    86016      // float pre[DHW]               (ends 4018176)
#define OFF_U      4018176    // bf16 U[9][DHW]               (ends 21712896)
// total 21.7 MB (< 57.1 MB proven available)

// ---------------------------------------------------------------- K1: setup
__global__ void k_setup(const float* __restrict__ proj,
                        const float* __restrict__ wreg,
                        float* __restrict__ M, float* __restrict__ wf) {
  if (threadIdx.x != 0) return;
  double P[NV][2][4][4];
  for (int v = 0; v < NV; ++v)
    for (int m = 0; m < 2; ++m)
      for (int i = 0; i < 4; ++i)
        for (int j = 0; j < 4; ++j)
          P[v][m][i][j] = (double)proj[((v * 2 + m) * 4 + i) * 4 + j];
  double C[NV][4][4];
  for (int v = 0; v < NV; ++v) {
    for (int i = 0; i < 4; ++i)
      for (int j = 0; j < 4; ++j) C[v][i][j] = P[v][0][i][j];
    for (int i = 0; i < 3; ++i)
      for (int j = 0; j < 4; ++j) {
        double s = 0.0;
        for (int k = 0; k < 3; ++k) s += P[v][1][i][k] * P[v][0][k][j];
        C[v][i][j] = s;
      }
  }
  double a[4][8];
  for (int i = 0; i < 4; ++i)
    for (int j = 0; j < 4; ++j) { a[i][j] = C[0][i][j]; a[i][j + 4] = (i == j) ? 1.0 : 0.0; }
  for (int col = 0; col < 4; ++col) {
    int piv = col; double best = fabs(a[col][col]);
    for (int r = col + 1; r < 4; ++r) { double v = fabs(a[r][col]); if (v > best) { best = v; piv = r; } }
    if (piv != col)
      for (int j = 0; j < 8; ++j) { double t = a[col][j]; a[col][j] = a[piv][j]; a[piv][j] = t; }
    double pv = a[col][col];
    for (int j = 0; j < 8; ++j) a[col][j] /= pv;
    for (int r = 0; r < 4; ++r) if (r != col) {
      double f = a[r][col];
      for (int j = 0; j < 8; ++j) a[r][j] -= f * a[col][j];
    }
  }
  double inv[4][4];
  for (int i = 0; i < 4; ++i)
    for (int j = 0; j < 4; ++j) inv[i][j] = a[i][j + 4];
  for (int v = 1; v < NV; ++v) {
    float* m = M + (v - 1) * 12;
    for (int i = 0; i < 3; ++i) {
      double r[4] = {0, 0, 0, 0};
      for (int k = 0; k < 4; ++k) {
        double cv = C[v][i][k];
        for (int j = 0; j < 4; ++j) r[j] += cv * inv[k][j];
      }
      m[i * 3 + 0] = (float)r[0]; m[i * 3 + 1] = (float)r[1]; m[i * 3 + 2] = (float)r[2];
      m[9 + i] = (float)r[3];
    }
  }
  for (int c = 0; c < NC; ++c) {
    for (int t = 0; t < 27; ++t) wf[c * 28 + t] = wreg[c * 27 + t];
    wf[c * 28 + 27] = 0.f;
  }
}

// ---------------------- K2: warp + variance + contract + x-fold (block=320)
__global__ __launch_bounds__(320) void k_warpvar(
    const float* __restrict__ feat,    // [5][32][128][160] channel-first
    const float* __restrict__ depthv,  // [48]
    const float* __restrict__ M,       // [4][12]
    const float* __restrict__ wf,      // [32][28]
    __hip_bfloat16* __restrict__ U)    // [9][DHW]
{
  __shared__ __hip_bfloat16 lds[27 * 320];   // 17.3 KB
  int tid = threadIdx.x;
  int d = blockIdx.x / 64;                   // 64 blocks per depth slice
  int rem = (blockIdx.x % 64) * 320 + tid;   // pixel index in [0, HW)
  int y = rem / NW;
  int x = rem % NW;
  int idx = d * HW + rem;
  float xf = (float)x, yf = (float)y;
  float df = depthv[d];

  int   cidx[16];
  float cw[16];
#pragma unroll
  for (int v = 0; v < 4; ++v) {
    const float* m = M + v * 12;
    float rx = m[0] * xf + m[1] * yf + m[2];
    float ry = m[3] * xf + m[4] * yf + m[5];
    float rz = m[6] * xf + m[7] * yf + m[8];
    float px = rx * df + m[9];
    float py = ry * df + m[10];
    float pz = rz * df + m[11];
    float gx = px / pz;
    float gy = py / pz;
    float x0 = floorf(gx), y0 = floorf(gy);
    float wx = gx - x0, wy = gy - y0;
    float cxs[2] = {x0, x0 + 1.f}, cys[2] = {y0, y0 + 1.f};
    float wxs[2] = {1.f - wx, wx}, wys[2] = {1.f - wy, wy};
#pragma unroll
    for (int cy = 0; cy < 2; ++cy)
#pragma unroll
      for (int cx = 0; cx < 2; ++cx) {
        float fx = cxs[cx], fy = cys[cy];
        bool valid = (fx >= 0.f) && (fx <= (float)(NW - 1)) &&
                     (fy >= 0.f) && (fy <= (float)(NH - 1));
        float fxc = fminf(fmaxf(fx, 0.f), (float)(NW - 1));
        float fyc = fminf(fmaxf(fy, 0.f), (float)(NH - 1));
        int xi = (int)fxc, yi = (int)fyc;
        cidx[v * 4 + cy * 2 + cx] = yi * NW + xi;
        cw[v * 4 + cy * 2 + cx] = wxs[cx] * wys[cy] * (valid ? 1.f : 0.f);
      }
  }

  int pix = y * NW + x;
  f32x2 wv2[14];
#pragma unroll
  for (int u = 0; u < 14; ++u) wv2[u] = (f32x2){0.f, 0.f};

#pragma unroll
  for (int c = 0; c < NC; ++c) {
    float f0 = feat[c * HW + pix];             // wave-coalesced
    float vs = f0, vq = f0 * f0;
#pragma unroll
    for (int v = 0; v < 4; ++v) {
      const float* fv = feat + ((size_t)((v + 1) * NC + c)) * HW;  // uniform base
      float val = cw[v * 4 + 0] * fv[cidx[v * 4 + 0]]
                + cw[v * 4 + 1] * fv[cidx[v * 4 + 1]]
                + cw[v * 4 + 2] * fv[cidx[v * 4 + 2]]
                + cw[v * 4 + 3] * fv[cidx[v * 4 + 3]];
      vs += val;
      vq += val * val;
    }
    float var = vq * 0.2f - (vs * 0.2f) * (vs * 0.2f);
    const f32x2* wrow = (const f32x2*)(wf + c * 28);
    f32x2 vv; vv.x = var; vv.y = var;
#pragma unroll
    for (int u = 0; u < 14; ++u) wv2[u] += wrow[u] * vv;
  }

  // x-fold: U_{dd,i}(x) = sum_j valid(x+j-1) * WV_{dd,i,j}(x+j-1)
  // block = 320 = 2 full rows, so x==0 / x==NW-1 coincide with tid 0/159/160/319.
#pragma unroll
  for (int t = 0; t < 27; ++t)
    lds[t * 320 + tid] = __float2bfloat16((t & 1) ? wv2[t >> 1].y : wv2[t >> 1].x);
  __syncthreads();

  bool xm = (x > 0), xp = (x < NW - 1);
  int tl = xm ? tid - 1 : tid;
  int tr = xp ? tid + 1 : tid;
#pragma unroll
  for (int t9 = 0; t9 < 9; ++t9) {
    float s  = __bfloat162float(lds[(t9 * 3 + 1) * 320 + tid]);
    float sl = __bfloat162float(lds[(t9 * 3 + 0) * 320 + tl]);
    float sr = __bfloat162float(lds[(t9 * 3 + 2) * 320 + tr]);
    s += (xm ? sl : 0.f) + (xp ? sr : 0.f);
    U[(size_t)t9 * DHW + idx] = __float2bfloat16(s);
  }
}

// ------------------------------------------------- K3a: 9-tap gather (d,y)
__global__ __launch_bounds__(256) void k_conv(const __hip_bfloat16* __restrict__ U,
                                              float* __restrict__ pre) {
  int idx = blockIdx.x * 256 + threadIdx.x;
  int x = idx % NW;
  int t1 = idx / NW;
  int y = t1 % NH;
  int d = t1 / NH;
  float acc = 0.f;
#pragma unroll
  for (int dd = 0; dd < 3; ++dd) {
    int dp = d + dd - 1;
    bool dok = (dp >= 0) && (dp < ND);
    int dpc = min(max(dp, 0), ND - 1);
#pragma unroll
    for (int i = 0; i < 3; ++i) {
      int yp = y + i - 1;
      bool yok = (yp >= 0) && (yp < NH);
      int ypc = min(max(yp, 0), NH - 1);
      int t9 = dd * 3 + i;
      float v = __bfloat162float(U[(size_t)t9 * DHW + dpc * HW + ypc * NW + x]);
      acc += (dok && yok) ? v : 0.f;
    }
  }
  pre[idx] = acc;
}

// ---------------------------------------- K3b: softmax over D + depth + conf
__global__ __launch_bounds__(256) void k_softmax(const float* __restrict__ pre,
                                                 const float* __restrict__ depthv,
                                                 float* __restrict__ depthf,
                                                 float* __restrict__ out_depth,
                                                 float* __restrict__ out_conf) {
  int p = blockIdx.x * 256 + threadIdx.x;
  float pr[ND];
  float m = -1e30f;
#pragma unroll
  for (int d = 0; d < ND; ++d) { pr[d] = pre[d * HW + p]; m = fmaxf(m, pr[d]); }
  float s = 0.f;
#pragma unroll
  for (int d = 0; d < ND; ++d) { pr[d] = expf(pr[d] - m); s += pr[d]; }
  float inv = 1.f / s;
  float dep = 0.f, ti = 0.f;
#pragma unroll
  for (int d = 0; d < ND; ++d) {
    float prob = pr[d] * inv;
    pr[d] = prob;
    dep += prob * depthv[d];
    ti += prob * (float)d;
  }
  int di = (int)ti;
  di = di < 0 ? 0 : (di > ND - 1 ? ND - 1 : di);
  float conf = 0.f;
#pragma unroll
  for (int d = 0; d < ND; ++d)
    conf += (d >= di - 1 && d <= di + 2) ? pr[d] : 0.f;
  depthf[p] = dep;
  out_depth[p] = dep;
  out_conf[p] = conf;
}

// ------------------------------- K4: convex upsample, block=(y,dy), 640 thr
__global__ __launch_bounds__(640) void k_upsample(const float* __restrict__ mask,
                                                  const float* __restrict__ depthf,
                                                  float* __restrict__ out) {
  __shared__ float row[NW * 8];
  int y = blockIdx.x >> 3;
  int dy = blockIdx.x & 7;
#pragma unroll
  for (int rep = 0; rep < 2; ++rep) {
    int lin = rep * 640 + threadIdx.x;     // [0, 1280)
    int dx = lin / NW;
    int x = lin % NW;
    float mv[9];
    float mmax = -1e30f;
#pragma unroll
    for (int k = 0; k < 9; ++k) {
      mv[k] = mask[(size_t)(k * 64 + dy * 8 + dx) * HW + y * NW + x];  // coalesced in x
      mmax = fmaxf(mmax, mv[k]);
    }
    float s = 0.f;
#pragma unroll
    for (int k = 0; k < 9; ++k) { mv[k] = expf(mv[k] - mmax); s += mv[k]; }
    float acc = 0.f;
#pragma unroll
    for (int k = 0; k < 9; ++k) {
      int ky = y + k / 3 - 1;
      int kx = x + k % 3 - 1;
      bool ok = (ky >= 0) && (ky < NH) && (kx >= 0) && (kx < NW);
      int kyc = min(max(ky, 0), NH - 1);
      int kxc = min(max(kx, 0), NW - 1);
      float dv = depthf[kyc * NW + kxc];
      acc += mv[k] * (ok ? dv : 0.f);
    }
    row[x * 8 + dx] = acc / s;
  }
  __syncthreads();
  float* orow = out + (size_t)(y * 8 + dy) * (NW * 8);
#pragma unroll
  for (int rep = 0; rep < 2; ++rep) {
    int j = rep * 640 + threadIdx.x;
    orow[j] = row[j];                      // coalesced
  }
}

// ---------------------------------------------------------------- launcher
extern "C" void kernel_launch(void* const* d_in, const int* in_sizes, int n_in,
                              void* d_out, int out_size, void* d_ws, size_t ws_size,
                              hipStream_t stream) {
  const float* feat   = (const float*)d_in[0];
  const float* proj   = (const float*)d_in[1];
  const float* depthv = (const float*)d_in[2];
  const float* mask   = (const float*)d_in[3];
  const float* wreg   = (const float*)d_in[4];

  char* ws = (char*)d_ws;
  float* M       = (float*)(ws + OFF_M);
  float* wf      = (float*)(ws + OFF_WF);
  float* depthf  = (float*)(ws + OFF_DEPTHF);
  float* pre     = (float*)(ws + OFF_PRE);
  __hip_bfloat16* U = (__hip_bfloat16*)(ws + OFF_U);

  float* out = (float*)d_out;
  float* out_depth = out + (NH * 8) * (NW * 8);
  float* out_conf  = out_depth + HW;

  k_setup<<<1, 64, 0, stream>>>(proj, wreg, M, wf);
  k_warpvar<<<DHW / 320, 320, 0, stream>>>(feat, depthv, M, wf, U);
  k_conv<<<DHW / 256, 256, 0, stream>>>(U, pre);
  k_softmax<<<HW / 256, 256, 0, stream>>>(pre, depthv, depthf, out_depth, out_conf);
  k_upsample<<<NH * 8, 640, 0, stream>>>(mask, depthf, out);
}

// Round 6
// 276.448 us; speedup vs baseline: 1.7095x; 1.2333x over previous
//
#include <hip/hip_runtime.h>
#include <hip/hip_bf16.h>

// Effi_MVS: B=1, V=5, C=32, D=48, H=128, W=160, RATIO=8. fp32 in, fp32 out.
// Round 6: k_warpvar is VMEM-issue bound (r3 model: 544 gathers/thread x ~11cyc
// ~= 150us measured). Changes vs r5:
//  - REVERT LDS x-fold (cost ~80us of latency exposure at 5-wave blocks /
//    barrier; saved only ~5us of write BW). Back to 27-plane bf16 WV output,
//    block=256.
//  - PAIR GATHERS: x-adjacent corners load as one dwordx2; boundary cases
//    folded into per-view weights (left->p1 iff x0>=W-1, right->p0 iff x0<0).
//    544 -> 288 loads/thread. All clamps in float before int cast.
//  - keep r4's coalesced k_upsample, r3's 27-tap k_conv.

#define NV 5
#define NC 32
#define ND 48
#define NH 128
#define NW 160
#define HW (NH * NW)
#define DHW (ND * HW)

typedef __attribute__((ext_vector_type(2))) float f32x2;
typedef __attribute__((ext_vector_type(2), aligned(4))) float f32x2u;  // 4B-aligned pair load

// ws layout (bytes)
#define OFF_M      0          // float M[4][12]
#define OFF_WF     256        // float wf[32][28]
#define OFF_DEPTHF 4096       // float depthf[20480]          (ends 86016)
#define OFF_PRE    86016      // float pre[DHW]               (ends 4018176)
#define OFF_WV     4018176    // bf16 WV[27][DHW]             (ends 57102336)
// total 57.1 MB (proven available in r3)

// ---------------------------------------------------------------- K1: setup
__global__ void k_setup(const float* __restrict__ proj,
                        const float* __restrict__ wreg,
                        float* __restrict__ M, float* __restrict__ wf) {
  if (threadIdx.x != 0) return;
  double P[NV][2][4][4];
  for (int v = 0; v < NV; ++v)
    for (int m = 0; m < 2; ++m)
      for (int i = 0; i < 4; ++i)
        for (int j = 0; j < 4; ++j)
          P[v][m][i][j] = (double)proj[((v * 2 + m) * 4 + i) * 4 + j];
  double C[NV][4][4];
  for (int v = 0; v < NV; ++v) {
    for (int i = 0; i < 4; ++i)
      for (int j = 0; j < 4; ++j) C[v][i][j] = P[v][0][i][j];
    for (int i = 0; i < 3; ++i)
      for (int j = 0; j < 4; ++j) {
        double s = 0.0;
        for (int k = 0; k < 3; ++k) s += P[v][1][i][k] * P[v][0][k][j];
        C[v][i][j] = s;
      }
  }
  double a[4][8];
  for (int i = 0; i < 4; ++i)
    for (int j = 0; j < 4; ++j) { a[i][j] = C[0][i][j]; a[i][j + 4] = (i == j) ? 1.0 : 0.0; }
  for (int col = 0; col < 4; ++col) {
    int piv = col; double best = fabs(a[col][col]);
    for (int r = col + 1; r < 4; ++r) { double v = fabs(a[r][col]); if (v > best) { best = v; piv = r; } }
    if (piv != col)
      for (int j = 0; j < 8; ++j) { double t = a[col][j]; a[col][j] = a[piv][j]; a[piv][j] = t; }
    double pv = a[col][col];
    for (int j = 0; j < 8; ++j) a[col][j] /= pv;
    for (int r = 0; r < 4; ++r) if (r != col) {
      double f = a[r][col];
      for (int j = 0; j < 8; ++j) a[r][j] -= f * a[col][j];
    }
  }
  double inv[4][4];
  for (int i = 0; i < 4; ++i)
    for (int j = 0; j < 4; ++j) inv[i][j] = a[i][j + 4];
  for (int v = 1; v < NV; ++v) {
    float* m = M + (v - 1) * 12;
    for (int i = 0; i < 3; ++i) {
      double r[4] = {0, 0, 0, 0};
      for (int k = 0; k < 4; ++k) {
        double cv = C[v][i][k];
        for (int j = 0; j < 4; ++j) r[j] += cv * inv[k][j];
      }
      m[i * 3 + 0] = (float)r[0]; m[i * 3 + 1] = (float)r[1]; m[i * 3 + 2] = (float)r[2];
      m[9 + i] = (float)r[3];
    }
  }
  for (int c = 0; c < NC; ++c) {
    for (int t = 0; t < 27; ++t) wf[c * 28 + t] = wreg[c * 27 + t];
    wf[c * 28 + 27] = 0.f;
  }
}

// ----------------------- K2: warp + variance + channel-contract (block=256)
__global__ __launch_bounds__(256) void k_warpvar(
    const float* __restrict__ feat,    // [5][32][128][160] channel-first
    const float* __restrict__ depthv,  // [48]
    const float* __restrict__ M,       // [4][12]
    const float* __restrict__ wf,      // [32][28]
    __hip_bfloat16* __restrict__ WV)   // [27][DHW]
{
  int idx = blockIdx.x * 256 + threadIdx.x;
  int x = idx % NW;
  int t1 = idx / NW;
  int y = t1 % NH;
  int d = t1 / NH;
  float xf = (float)x, yf = (float)y;
  float df = depthv[d];

  int   r0i[4], r1i[4];          // row base offsets (pair start) per view
  float W00[4], W10[4], W01[4], W11[4];
#pragma unroll
  for (int v = 0; v < 4; ++v) {
    const float* m = M + v * 12;
    float rx = m[0] * xf + m[1] * yf + m[2];
    float ry = m[3] * xf + m[4] * yf + m[5];
    float rz = m[6] * xf + m[7] * yf + m[8];
    float px = rx * df + m[9];
    float py = ry * df + m[10];
    float pz = rz * df + m[11];
    float gx = px / pz;
    float gy = py / pz;
    float x0f = floorf(gx), y0f = floorf(gy);
    float wx = gx - x0f, wy = gy - y0f;
    // per-corner validity (pre-clamp)
    float vx0 = (x0f >= 0.f && x0f <= (float)(NW - 1)) ? 1.f : 0.f;
    float vx1 = (x0f + 1.f >= 0.f && x0f + 1.f <= (float)(NW - 1)) ? 1.f : 0.f;
    float vy0 = (y0f >= 0.f && y0f <= (float)(NH - 1)) ? 1.f : 0.f;
    float vy1 = (y0f + 1.f >= 0.f && y0f + 1.f <= (float)(NH - 1)) ? 1.f : 0.f;
    // pair base (clamped in float, then cast — no int overflow)
    float xbf = fminf(fmaxf(x0f, 0.f), (float)(NW - 2));
    int xb = (int)xbf;
    float wl = (1.f - wx) * vx0;     // left-corner weight (incl. x-validity)
    float wr = wx * vx1;             // right-corner weight
    bool leftIsP1 = (x0f > (float)(NW - 2));   // x0 == W-1 -> value at p1
    bool rightIsP0 = (x0f < 0.f);              // x0 == -1  -> right value at p0
    float ax = (leftIsP1 ? 0.f : wl) + (rightIsP0 ? wr : 0.f);  // weight on p0
    float bx = (leftIsP1 ? wl : 0.f) + (rightIsP0 ? 0.f : wr);  // weight on p1
    float yb0f = fminf(fmaxf(y0f, 0.f), (float)(NH - 1));
    float yb1f = fminf(fmaxf(y0f + 1.f, 0.f), (float)(NH - 1));
    r0i[v] = (int)yb0f * NW + xb;
    r1i[v] = (int)yb1f * NW + xb;
    float wy0 = (1.f - wy) * vy0, wy1 = wy * vy1;
    W00[v] = ax * wy0; W10[v] = bx * wy0;
    W01[v] = ax * wy1; W11[v] = bx * wy1;
  }

  int pix = y * NW + x;
  f32x2 wv2[14];
#pragma unroll
  for (int u = 0; u < 14; ++u) wv2[u] = (f32x2){0.f, 0.f};

#pragma unroll
  for (int c = 0; c < NC; ++c) {
    float f0 = feat[c * HW + pix];             // wave-coalesced ref load
    float vs = f0, vq = f0 * f0;
#pragma unroll
    for (int v = 0; v < 4; ++v) {
      const float* fv = feat + ((size_t)((v + 1) * NC + c)) * HW;
      f32x2u q0 = *(const f32x2u*)(fv + r0i[v]);   // dwordx2 pair, row y0
      f32x2u q1 = *(const f32x2u*)(fv + r1i[v]);   // dwordx2 pair, row y0+1
      float val = W00[v] * q0.x + W10[v] * q0.y
                + W01[v] * q1.x + W11[v] * q1.y;
      vs += val;
      vq += val * val;
    }
    float var = vq * 0.2f - (vs * 0.2f) * (vs * 0.2f);
    const f32x2* wrow = (const f32x2*)(wf + c * 28);
    f32x2 vv; vv.x = var; vv.y = var;
#pragma unroll
    for (int u = 0; u < 14; ++u) wv2[u] += wrow[u] * vv;   // v_pk_fma_f32
  }

#pragma unroll
  for (int u = 0; u < 14; ++u) {
    int t0 = 2 * u;
    WV[(size_t)t0 * DHW + idx] = __float2bfloat16(wv2[u].x);
    if (t0 + 1 < 27) WV[(size_t)(t0 + 1) * DHW + idx] = __float2bfloat16(wv2[u].y);
  }
}

// ------------------------------------------------- K3a: 27-tap gather (conv)
__global__ __launch_bounds__(256) void k_conv(const __hip_bfloat16* __restrict__ WV,
                                              float* __restrict__ pre) {
  int idx = blockIdx.x * 256 + threadIdx.x;
  int x = idx % NW;
  int t1 = idx / NW;
  int y = t1 % NH;
  int d = t1 / NH;
  float acc = 0.f;
#pragma unroll
  for (int dd = 0; dd < 3; ++dd) {
    int dp = d + dd - 1;
    bool dok = (dp >= 0) && (dp < ND);
    int dpc = min(max(dp, 0), ND - 1);
#pragma unroll
    for (int i = 0; i < 3; ++i) {
      int yp = y + i - 1;
      bool yok = (yp >= 0) && (yp < NH);
      int ypc = min(max(yp, 0), NH - 1);
#pragma unroll
      for (int j = 0; j < 3; ++j) {
        int xp = x + j - 1;
        bool xok = (xp >= 0) && (xp < NW);
        int xpc = min(max(xp, 0), NW - 1);
        int t = dd * 9 + i * 3 + j;
        float v = __bfloat162float(WV[(size_t)t * DHW + dpc * HW + ypc * NW + xpc]);
        acc += (dok && yok && xok) ? v : 0.f;
      }
    }
  }
  pre[idx] = acc;
}

// ---------------------------------------- K3b: softmax over D + depth + conf
__global__ __launch_bounds__(256) void k_softmax(const float* __restrict__ pre,
                                                 const float* __restrict__ depthv,
                                                 float* __restrict__ depthf,
                                                 float* __restrict__ out_depth,
                                                 float* __restrict__ out_conf) {
  int p = blockIdx.x * 256 + threadIdx.x;
  float pr[ND];
  float m = -1e30f;
#pragma unroll
  for (int d = 0; d < ND; ++d) { pr[d] = pre[d * HW + p]; m = fmaxf(m, pr[d]); }
  float s = 0.f;
#pragma unroll
  for (int d = 0; d < ND; ++d) { pr[d] = expf(pr[d] - m); s += pr[d]; }
  float inv = 1.f / s;
  float dep = 0.f, ti = 0.f;
#pragma unroll
  for (int d = 0; d < ND; ++d) {
    float prob = pr[d] * inv;
    pr[d] = prob;
    dep += prob * depthv[d];
    ti += prob * (float)d;
  }
  int di = (int)ti;
  di = di < 0 ? 0 : (di > ND - 1 ? ND - 1 : di);
  float conf = 0.f;
#pragma unroll
  for (int d = 0; d < ND; ++d)
    conf += (d >= di - 1 && d <= di + 2) ? pr[d] : 0.f;
  depthf[p] = dep;
  out_depth[p] = dep;
  out_conf[p] = conf;
}

// ------------------------------- K4: convex upsample, block=(y,dy), 640 thr
__global__ __launch_bounds__(640) void k_upsample(const float* __restrict__ mask,
                                                  const float* __restrict__ depthf,
                                                  float* __restrict__ out) {
  __shared__ float row[NW * 8];
  int y = blockIdx.x >> 3;
  int dy = blockIdx.x & 7;
#pragma unroll
  for (int rep = 0; rep < 2; ++rep) {
    int lin = rep * 640 + threadIdx.x;     // [0, 1280)
    int dx = lin / NW;
    int x = lin % NW;
    float mv[9];
    float mmax = -1e30f;
#pragma unroll
    for (int k = 0; k < 9; ++k) {
      mv[k] = mask[(size_t)(k * 64 + dy * 8 + dx) * HW + y * NW + x];  // coalesced in x
      mmax = fmaxf(mmax, mv[k]);
    }
    float s = 0.f;
#pragma unroll
    for (int k = 0; k < 9; ++k) { mv[k] = expf(mv[k] - mmax); s += mv[k]; }
    float acc = 0.f;
#pragma unroll
    for (int k = 0; k < 9; ++k) {
      int ky = y + k / 3 - 1;
      int kx = x + k % 3 - 1;
      bool ok = (ky >= 0) && (ky < NH) && (kx >= 0) && (kx < NW);
      int kyc = min(max(ky, 0), NH - 1);
      int kxc = min(max(kx, 0), NW - 1);
      float dv = depthf[kyc * NW + kxc];
      acc += mv[k] * (ok ? dv : 0.f);
    }
    row[x * 8 + dx] = acc / s;
  }
  __syncthreads();
  float* orow = out + (size_t)(y * 8 + dy) * (NW * 8);
#pragma unroll
  for (int rep = 0; rep < 2; ++rep) {
    int j = rep * 640 + threadIdx.x;
    orow[j] = row[j];                      // coalesced
  }
}

// ---------------------------------------------------------------- launcher
extern "C" void kernel_launch(void* const* d_in, const int* in_sizes, int n_in,
                              void* d_out, int out_size, void* d_ws, size_t ws_size,
                              hipStream_t stream) {
  const float* feat   = (const float*)d_in[0];
  const float* proj   = (const float*)d_in[1];
  const float* depthv = (const float*)d_in[2];
  const float* mask   = (const float*)d_in[3];
  const float* wreg   = (const float*)d_in[4];

  char* ws = (char*)d_ws;
  float* M       = (float*)(ws + OFF_M);
  float* wf      = (float*)(ws + OFF_WF);
  float* depthf  = (float*)(ws + OFF_DEPTHF);
  float* pre     = (float*)(ws + OFF_PRE);
  __hip_bfloat16* WV = (__hip_bfloat16*)(ws + OFF_WV);

  float* out = (float*)d_out;
  float* out_depth = out + (NH * 8) * (NW * 8);
  float* out_conf  = out_depth + HW;

  k_setup<<<1, 64, 0, stream>>>(proj, wreg, M, wf);
  k_warpvar<<<DHW / 256, 256, 0, stream>>>(feat, depthv, M, wf, WV);
  k_conv<<<DHW / 256, 256, 0, stream>>>(WV, pre);
  k_softmax<<<HW / 256, 256, 0, stream>>>(pre, depthv, depthf, out_depth, out_conf);
  k_upsample<<<NH * 8, 640, 0, stream>>>(mask, depthf, out);
}